// Round 1
// baseline (284.344 us; speedup 1.0000x reference)
//
#include <hip/hip_runtime.h>
#include <math.h>

// HardNegativeMiner: per row, mask labels[row], take top-5 indices of the rest.
// B=8192 rows, C=50257 fp32 logits. One wave64 per row; streaming top-5 in
// registers; butterfly shfl_xor argmax merge.

constexpr int kC = 50257;

__global__ __launch_bounds__(256)
void hnm_topk_kernel(const float* __restrict__ logits,
                     const int* __restrict__ labels,
                     int* __restrict__ out,
                     int B)
{
    const int lane = threadIdx.x & 63;
    const int row  = blockIdx.x * 4 + (threadIdx.x >> 6);
    if (row >= B) return;

    const int label = labels[row];
    const float* __restrict__ rp = logits + (size_t)row * kC;

    // Per-lane top-5, descending. Named scalars only (avoid scratch spills
    // from runtime-indexed arrays).
    float v0 = -INFINITY, v1 = -INFINITY, v2 = -INFINITY, v3 = -INFINITY, v4 = -INFINITY;
    int   i0 = 0, i1 = 0, i2 = 0, i3 = 0, i4 = 0;

#define TRY_INSERT(VAL, ID)                                                       \
    do {                                                                          \
        float _v = (VAL); int _id = (ID);                                         \
        if (_v > v4 && _id != label) {                                            \
            if (_v > v2) {                                                        \
                if (_v > v0)      { v4=v3;i4=i3; v3=v2;i3=i2; v2=v1;i2=i1;        \
                                    v1=v0;i1=i0; v0=_v;i0=_id; }                  \
                else if (_v > v1) { v4=v3;i4=i3; v3=v2;i3=i2; v2=v1;i2=i1;        \
                                    v1=_v;i1=_id; }                               \
                else              { v4=v3;i4=i3; v3=v2;i3=i2; v2=_v;i2=_id; }     \
            } else {                                                              \
                if (_v > v3)      { v4=v3;i4=i3; v3=_v;i3=_id; }                  \
                else              { v4=_v;i4=_id; }                               \
            }                                                                     \
        }                                                                         \
    } while (0)

    // C % 4 == 1, so (row*C) % 4 == row % 4: scalar prologue of s elements
    // restores 16B alignment for float4 loads.
    const int s = (4 - (row & 3)) & 3;
    if (lane < s) {
        TRY_INSERT(rp[lane], lane);
    }

    const int nvec = (kC - s) >> 2;                 // aligned float4 count
    const float4* __restrict__ vp = (const float4*)(rp + s);
    for (int j = lane; j < nvec; j += 64) {
        float4 q = vp[j];
        int base = s + (j << 2);
        TRY_INSERT(q.x, base + 0);
        TRY_INSERT(q.y, base + 1);
        TRY_INSERT(q.z, base + 2);
        TRY_INSERT(q.w, base + 3);
    }

    // Tail scalars ((kC - s) % 4 of them).
    {
        int t = s + (nvec << 2) + lane;
        if (t < kC) TRY_INSERT(rp[t], t);
    }

    // Merge 64 per-lane top-5 lists -> global top-5. 5 rounds of butterfly
    // argmax over (value desc, index asc); winner lane pops its list head.
#pragma unroll
    for (int k = 0; k < 5; ++k) {
        float bv = v0; int bi = i0; int bl = lane;
#pragma unroll
        for (int d = 32; d >= 1; d >>= 1) {
            float ov = __shfl_xor(bv, d, 64);
            int   oi = __shfl_xor(bi, d, 64);
            int   ol = __shfl_xor(bl, d, 64);
            if (ov > bv || (ov == bv && oi < bi)) { bv = ov; bi = oi; bl = ol; }
        }
        if (lane == 0) out[row * 5 + k] = bi;
        if (lane == bl) {
            v0=v1;i0=i1; v1=v2;i1=i2; v2=v3;i2=i3; v3=v4;i3=i4; v4=-INFINITY;
        }
    }
#undef TRY_INSERT
}

extern "C" void kernel_launch(void* const* d_in, const int* in_sizes, int n_in,
                              void* d_out, int out_size, void* d_ws, size_t ws_size,
                              hipStream_t stream)
{
    const float* logits = (const float*)d_in[0];
    const int*   labels = (const int*)d_in[1];
    int*         out    = (int*)d_out;
    const int B = in_sizes[1];            // 8192 labels == number of rows

    dim3 block(256);                      // 4 waves -> 4 rows per block
    dim3 grid((B + 3) / 4);
    hipLaunchKernelGGL(hnm_topk_kernel, grid, block, 0, stream,
                       logits, labels, out, B);
}

// Round 3
// 270.066 us; speedup vs baseline: 1.0529x; 1.0529x over previous
//
#include <hip/hip_runtime.h>
#include <math.h>

// HardNegativeMiner: per row, mask labels[row], take top-5 indices of the rest.
// B=8192 rows, C=50257 fp32 logits. One wave64 per row.
//
// R3 = R2 with the nontemporal load type fixed (clang native vector, not
// HIP_vector_type). R2 changes vs R1 (284 µs, floor ~261 µs):
//  - per-lane TOP-6 with NO label check in the hot loop (label filtered at
//    merge time): removes a v_cmp+and per element (4.1e8 elements).
//  - unroll-by-2 with both float4 loads issued before consumption (2x MLP).
//  - nontemporal loads (pure stream, no reuse).

constexpr int kC = 50257;

typedef float vf4 __attribute__((ext_vector_type(4)));

__global__ __launch_bounds__(256)
void hnm_topk_kernel(const float* __restrict__ logits,
                     const int* __restrict__ labels,
                     int* __restrict__ out,
                     int B)
{
    const int lane = threadIdx.x & 63;
    const int row  = blockIdx.x * 4 + (threadIdx.x >> 6);
    if (row >= B) return;

    const int label = labels[row];
    const float* __restrict__ rp = logits + (size_t)row * kC;

    // Per-lane top-6, descending, named scalars (rule #20: no runtime-indexed
    // arrays -> no scratch).
    float v0=-INFINITY, v1=-INFINITY, v2=-INFINITY, v3=-INFINITY, v4=-INFINITY, v5=-INFINITY;
    int   i0=0, i1=0, i2=0, i3=0, i4=0, i5=0;

#define INS(VAL, ID)                                                              \
    do {                                                                          \
        float _v = (VAL);                                                         \
        if (_v > v5) {                                                            \
            int _id = (ID);                                                       \
            if (_v > v2) {                                                        \
                if (_v > v1) {                                                    \
                    if (_v > v0) { v5=v4;i5=i4; v4=v3;i4=i3; v3=v2;i3=i2;         \
                                   v2=v1;i2=i1; v1=v0;i1=i0; v0=_v;i0=_id; }      \
                    else         { v5=v4;i5=i4; v4=v3;i4=i3; v3=v2;i3=i2;         \
                                   v2=v1;i2=i1; v1=_v;i1=_id; }                   \
                } else           { v5=v4;i5=i4; v4=v3;i4=i3; v3=v2;i3=i2;         \
                                   v2=_v;i2=_id; }                                \
            } else {                                                              \
                if (_v > v4) {                                                    \
                    if (_v > v3) { v5=v4;i5=i4; v4=v3;i4=i3; v3=_v;i3=_id; }      \
                    else         { v5=v4;i5=i4; v4=_v;i4=_id; }                   \
                } else           { v5=_v;i5=_id; }                                \
            }                                                                     \
        }                                                                         \
    } while (0)

    // C % 4 == 1 -> (row*C) % 4 == row % 4: scalar prologue of s elements
    // restores 16B alignment for float4 loads.
    const int s = (4 - (row & 3)) & 3;
    if (lane < s) INS(rp[lane], lane);

    const int nvec = (kC - s) >> 2;                 // aligned float4 count
    const vf4* __restrict__ vp = (const vf4*)(rp + s);

    int j = lane;
    // Unrolled-by-2 main loop: issue both loads before consuming either.
    for (; j + 64 < nvec; j += 128) {
        vf4 q0 = __builtin_nontemporal_load(vp + j);
        vf4 q1 = __builtin_nontemporal_load(vp + j + 64);
        int b0 = s + (j << 2);
        INS(q0.x, b0 + 0); INS(q0.y, b0 + 1); INS(q0.z, b0 + 2); INS(q0.w, b0 + 3);
        int b1 = b0 + 256;
        INS(q1.x, b1 + 0); INS(q1.y, b1 + 1); INS(q1.z, b1 + 2); INS(q1.w, b1 + 3);
    }
    for (; j < nvec; j += 64) {
        vf4 q = __builtin_nontemporal_load(vp + j);
        int b = s + (j << 2);
        INS(q.x, b + 0); INS(q.y, b + 1); INS(q.z, b + 2); INS(q.w, b + 3);
    }

    // Tail scalars ((kC - s) % 4 of them).
    {
        int t = s + (nvec << 2) + lane;
        if (t < kC) INS(rp[t], t);
    }

    // Merge 64 per-lane top-6 lists -> pop global max 6 times, skipping the
    // label, writing the first 5 survivors. Butterfly argmax over
    // (value desc, index asc) matches jax.lax.top_k ordering.
    int wr = 0;
#pragma unroll
    for (int k = 0; k < 6; ++k) {
        float bv = v0; int bi = i0; int bl = lane;
#pragma unroll
        for (int d = 32; d >= 1; d >>= 1) {
            float ov = __shfl_xor(bv, d, 64);
            int   oi = __shfl_xor(bi, d, 64);
            int   ol = __shfl_xor(bl, d, 64);
            if (ov > bv || (ov == bv && oi < bi)) { bv = ov; bi = oi; bl = ol; }
        }
        if (bi != label) {
            if (lane == 0 && wr < 5) out[row * 5 + wr] = bi;
            ++wr;
        }
        if (lane == bl) {
            v0=v1;i0=i1; v1=v2;i1=i2; v2=v3;i2=i3; v3=v4;i3=i4; v4=v5;i4=i5;
            v5=-INFINITY;
        }
    }
#undef INS
}

extern "C" void kernel_launch(void* const* d_in, const int* in_sizes, int n_in,
                              void* d_out, int out_size, void* d_ws, size_t ws_size,
                              hipStream_t stream)
{
    const float* logits = (const float*)d_in[0];
    const int*   labels = (const int*)d_in[1];
    int*         out    = (int*)d_out;
    const int B = in_sizes[1];            // 8192 labels == number of rows

    dim3 block(256);                      // 4 waves -> 4 rows per block
    dim3 grid((B + 3) / 4);
    hipLaunchKernelGGL(hnm_topk_kernel, grid, block, 0, stream,
                       logits, labels, out, B);
}

// Round 4
// 270.044 us; speedup vs baseline: 1.0530x; 1.0001x over previous
//
#include <hip/hip_runtime.h>
#include <math.h>

// HardNegativeMiner: per row, mask labels[row], take top-5 indices of the rest.
// B=8192 rows, C=50257 fp32 logits. One wave64 per row.
//
// R3 = R2 with the nontemporal load type fixed (clang native vector, not
// HIP_vector_type). R2 changes vs R1 (284 µs, floor ~261 µs):
//  - per-lane TOP-6 with NO label check in the hot loop (label filtered at
//    merge time): removes a v_cmp+and per element (4.1e8 elements).
//  - unroll-by-2 with both float4 loads issued before consumption (2x MLP).
//  - nontemporal loads (pure stream, no reuse).

constexpr int kC = 50257;

typedef float vf4 __attribute__((ext_vector_type(4)));

__global__ __launch_bounds__(256)
void hnm_topk_kernel(const float* __restrict__ logits,
                     const int* __restrict__ labels,
                     int* __restrict__ out,
                     int B)
{
    const int lane = threadIdx.x & 63;
    const int row  = blockIdx.x * 4 + (threadIdx.x >> 6);
    if (row >= B) return;

    const int label = labels[row];
    const float* __restrict__ rp = logits + (size_t)row * kC;

    // Per-lane top-6, descending, named scalars (rule #20: no runtime-indexed
    // arrays -> no scratch).
    float v0=-INFINITY, v1=-INFINITY, v2=-INFINITY, v3=-INFINITY, v4=-INFINITY, v5=-INFINITY;
    int   i0=0, i1=0, i2=0, i3=0, i4=0, i5=0;

#define INS(VAL, ID)                                                              \
    do {                                                                          \
        float _v = (VAL);                                                         \
        if (_v > v5) {                                                            \
            int _id = (ID);                                                       \
            if (_v > v2) {                                                        \
                if (_v > v1) {                                                    \
                    if (_v > v0) { v5=v4;i5=i4; v4=v3;i4=i3; v3=v2;i3=i2;         \
                                   v2=v1;i2=i1; v1=v0;i1=i0; v0=_v;i0=_id; }      \
                    else         { v5=v4;i5=i4; v4=v3;i4=i3; v3=v2;i3=i2;         \
                                   v2=v1;i2=i1; v1=_v;i1=_id; }                   \
                } else           { v5=v4;i5=i4; v4=v3;i4=i3; v3=v2;i3=i2;         \
                                   v2=_v;i2=_id; }                                \
            } else {                                                              \
                if (_v > v4) {                                                    \
                    if (_v > v3) { v5=v4;i5=i4; v4=v3;i4=i3; v3=_v;i3=_id; }      \
                    else         { v5=v4;i5=i4; v4=_v;i4=_id; }                   \
                } else           { v5=_v;i5=_id; }                                \
            }                                                                     \
        }                                                                         \
    } while (0)

    // C % 4 == 1 -> (row*C) % 4 == row % 4: scalar prologue of s elements
    // restores 16B alignment for float4 loads.
    const int s = (4 - (row & 3)) & 3;
    if (lane < s) INS(rp[lane], lane);

    const int nvec = (kC - s) >> 2;                 // aligned float4 count
    const vf4* __restrict__ vp = (const vf4*)(rp + s);

    int j = lane;
    // Unrolled-by-2 main loop: issue both loads before consuming either.
    for (; j + 64 < nvec; j += 128) {
        vf4 q0 = __builtin_nontemporal_load(vp + j);
        vf4 q1 = __builtin_nontemporal_load(vp + j + 64);
        int b0 = s + (j << 2);
        INS(q0.x, b0 + 0); INS(q0.y, b0 + 1); INS(q0.z, b0 + 2); INS(q0.w, b0 + 3);
        int b1 = b0 + 256;
        INS(q1.x, b1 + 0); INS(q1.y, b1 + 1); INS(q1.z, b1 + 2); INS(q1.w, b1 + 3);
    }
    for (; j < nvec; j += 64) {
        vf4 q = __builtin_nontemporal_load(vp + j);
        int b = s + (j << 2);
        INS(q.x, b + 0); INS(q.y, b + 1); INS(q.z, b + 2); INS(q.w, b + 3);
    }

    // Tail scalars ((kC - s) % 4 of them).
    {
        int t = s + (nvec << 2) + lane;
        if (t < kC) INS(rp[t], t);
    }

    // Merge 64 per-lane top-6 lists -> pop global max 6 times, skipping the
    // label, writing the first 5 survivors. Butterfly argmax over
    // (value desc, index asc) matches jax.lax.top_k ordering.
    int wr = 0;
#pragma unroll
    for (int k = 0; k < 6; ++k) {
        float bv = v0; int bi = i0; int bl = lane;
#pragma unroll
        for (int d = 32; d >= 1; d >>= 1) {
            float ov = __shfl_xor(bv, d, 64);
            int   oi = __shfl_xor(bi, d, 64);
            int   ol = __shfl_xor(bl, d, 64);
            if (ov > bv || (ov == bv && oi < bi)) { bv = ov; bi = oi; bl = ol; }
        }
        if (bi != label) {
            if (lane == 0 && wr < 5) out[row * 5 + wr] = bi;
            ++wr;
        }
        if (lane == bl) {
            v0=v1;i0=i1; v1=v2;i1=i2; v2=v3;i2=i3; v3=v4;i3=i4; v4=v5;i4=i5;
            v5=-INFINITY;
        }
    }
#undef INS
}

extern "C" void kernel_launch(void* const* d_in, const int* in_sizes, int n_in,
                              void* d_out, int out_size, void* d_ws, size_t ws_size,
                              hipStream_t stream)
{
    const float* logits = (const float*)d_in[0];
    const int*   labels = (const int*)d_in[1];
    int*         out    = (int*)d_out;
    const int B = in_sizes[1];            // 8192 labels == number of rows

    dim3 block(256);                      // 4 waves -> 4 rows per block
    dim3 grid((B + 3) / 4);
    hipLaunchKernelGGL(hnm_topk_kernel, grid, block, 0, stream,
                       logits, labels, out, B);
}